// Round 1
// baseline (49.192 us; speedup 1.0000x reference)
//
#include <hip/hip_runtime.h>

typedef unsigned short u16;
typedef _Float16 f16x2 __attribute__((ext_vector_type(2)));
typedef _Float16 f16x8 __attribute__((ext_vector_type(8)));
typedef float    f32x4  __attribute__((ext_vector_type(4)));
typedef float    f32x16 __attribute__((ext_vector_type(16)));

// Fragment k-map convention (same for A and B operands, so any within-lane
// permutation cancels in the MFMA contraction):
//   k_local(lane, j) = (lane>>5)*4 + (j&3) + 8*(j>>2),  j = 0..7
// D layout (measured m74/m101): col = lane&31, row = (r&3) + 8*(r>>2) + 4*(lane>>5)

union U4 { uint4 u; f16x8 h; u16 s[8]; };
union HU { f16x2 h2[4]; f16x8 h8; };

// ---------------------------------------------------------------------------
// Prep kernel: lay out W2flat (2080 x 32, f16) + W1 (16 x 64, f16) in MFMA
// B-fragment order into d_ws.
//   W2flat[kk][i] = kk < 2048 ? W2[kk>>5][i*32 + (kk&31)] : b2[i*32 + kk-2048]
// Bf slot (k2, lane): 8 f16 at ws + (k2*64 + lane)*8,  kk = k2*16 + k_local
// W1f slot (nt, lane): at ws + (8320 + nt*64 + lane)*8, col = nt*32 + (lane&31)
// ---------------------------------------------------------------------------
__global__ void prep_kernel(const float* __restrict__ W1,
                            const float* __restrict__ W2,
                            const float* __restrict__ b2,
                            u16* __restrict__ ws)
{
    int id = blockIdx.x * 256 + threadIdx.x;
    if (id < 8320) {                       // 130 ksteps * 64 lanes
        int k2 = id >> 6, l = id & 63;
        int h = l >> 5, col = l & 31;
        U4 o;
        #pragma unroll
        for (int g = 0; g < 2; ++g) {
            int base4 = k2 * 16 + g * 8 + h * 4;   // 4-aligned, no 32-straddle
            f32x4 v;
            if (base4 < 2048) {
                int k1 = base4 >> 5, j32 = base4 & 31;
                v = *(const f32x4*)&W2[k1 * 1024 + col * 32 + j32];
            } else {
                v = *(const f32x4*)&b2[col * 32 + (base4 - 2048)];
            }
            #pragma unroll
            for (int j = 0; j < 4; ++j)
                o.h[g * 4 + j] = (_Float16)v[j];
        }
        *(uint4*)(ws + id * 8) = o.u;
    } else if (id < 8448) {                // W1 fragments: 2 ntiles * 64 lanes
        int idx = id - 8320;
        int nt = idx >> 6, l = idx & 63;
        int h = l >> 5, col = nt * 32 + (l & 31);
        U4 o;
        #pragma unroll
        for (int g = 0; g < 2; ++g)
            #pragma unroll
            for (int j = 0; j < 4; ++j) {
                int k = g * 8 + h * 4 + j;
                o.h[g * 4 + j] = (_Float16)W1[k * 64 + col];
            }
        *(uint4*)(ws + id * 8) = o.u;
    }
}

// ---------------------------------------------------------------------------
// Main kernel: 4 waves/block, 96 edges/wave (3 M-tiles of 32).
// Per wave: layer-1 MFMA -> hdnT in wave-private LDS (stride 98 u16: conflict-
// free both transpose-write and K-loop read, 4B-aligned b32 writes), then
// K-loop k1 = 0..64 (row 64 = 1.0 handles the b2 bias rows), 6 MFMAs per k1.
// No __syncthreads needed anywhere.
// ---------------------------------------------------------------------------
#define STRIDE_T 98
#define SLICE_T  6400   // u16 per wave (need 64*98+96 = 6368)

__global__ __launch_bounds__(256, 3) void edge_kernel(
    const float* __restrict__ h_w,
    const float* __restrict__ ef,
    const float* __restrict__ b1,
    const u16*  __restrict__ ws,
    float* __restrict__ out,
    int E)
{
    __shared__ alignas(16) u16 ldsT[4 * SLICE_T];
    const int tid  = threadIdx.x;
    const int lane = tid & 63;
    const int wv   = tid >> 6;
    const int l31  = lane & 31;
    const int h    = lane >> 5;
    const int tileBase = (blockIdx.x * 4 + wv) * 96;
    if (tileBase >= E) return;
    u16* myT = ldsT + wv * SLICE_T;

    const uint4* Bf  = (const uint4*)ws;
    const uint4* W1f = (const uint4*)(ws + 8320 * 8);

    // ---------------- layer 1: hdn = relu(ef @ W1 + b1) ----------------
    U4 w0, w1;
    w0.u = W1f[lane];
    w1.u = W1f[64 + lane];
    const float bb0 = b1[l31], bb1 = b1[32 + l31];
    #pragma unroll
    for (int mt = 0; mt < 3; ++mt) {
        int e = tileBase + mt * 32 + l31;
        bool ok = e < E;
        f32x4 g0 = {}, g1 = {};
        if (ok) {
            g0 = *(const f32x4*)&ef[e * 16 + h * 4];
            g1 = *(const f32x4*)&ef[e * 16 + 8 + h * 4];
        }
        U4 a;
        #pragma unroll
        for (int j = 0; j < 4; ++j) {
            a.h[j]     = (_Float16)g0[j];
            a.h[4 + j] = (_Float16)g1[j];
        }
        f32x16 c0 = {}, c1 = {};
        c0 = __builtin_amdgcn_mfma_f32_32x32x16_f16(a.h, w0.h, c0, 0, 0, 0);
        c1 = __builtin_amdgcn_mfma_f32_32x32x16_f16(a.h, w1.h, c1, 0, 0, 0);
        // relu + bias, pack edge-pairs, transposed write hdnT[k1][e_local]
        #pragma unroll
        for (int nt = 0; nt < 2; ++nt) {
            float bb = nt ? bb1 : bb0;
            int k1 = nt * 32 + l31;
            #pragma unroll
            for (int rp = 0; rp < 8; ++rp) {
                int r = 2 * rp;
                float v0 = fmaxf((nt ? c1[r]     : c0[r])     + bb, 0.f);
                float v1 = fmaxf((nt ? c1[r + 1] : c0[r + 1]) + bb, 0.f);
                f16x2 p = { (_Float16)v0, (_Float16)v1 };
                int e0 = mt * 32 + (r & 3) + 8 * (r >> 2) + 4 * h; // even
                *(unsigned int*)(myT + k1 * STRIDE_T + e0) =
                    __builtin_bit_cast(unsigned int, p);
            }
        }
    }
    // bias row k1 = 64: hdn = 1.0 (feeds the b2 rows of W2flat)
    if (lane < 48)
        *(unsigned int*)(myT + 64 * STRIDE_T + lane * 2) = 0x3C003C00u;

    // ---------------- load h_w fragments (f16, kept in regs) ----------------
    f16x2 hwA[3][2][4];
    #pragma unroll
    for (int mt = 0; mt < 3; ++mt) {
        int e = tileBase + mt * 32 + l31;
        bool ok = e < E;
        f32x4 q0 = {}, q1 = {}, q2 = {}, q3 = {};
        if (ok) {
            const float* hp = h_w + (size_t)e * 32 + h * 4;
            q0 = *(const f32x4*)(hp);
            q1 = *(const f32x4*)(hp + 8);
            q2 = *(const f32x4*)(hp + 16);
            q3 = *(const f32x4*)(hp + 24);
        }
        hwA[mt][0][0] = f16x2{ (_Float16)q0[0], (_Float16)q0[1] };
        hwA[mt][0][1] = f16x2{ (_Float16)q0[2], (_Float16)q0[3] };
        hwA[mt][0][2] = f16x2{ (_Float16)q1[0], (_Float16)q1[1] };
        hwA[mt][0][3] = f16x2{ (_Float16)q1[2], (_Float16)q1[3] };
        hwA[mt][1][0] = f16x2{ (_Float16)q2[0], (_Float16)q2[1] };
        hwA[mt][1][1] = f16x2{ (_Float16)q2[2], (_Float16)q2[3] };
        hwA[mt][1][2] = f16x2{ (_Float16)q3[0], (_Float16)q3[1] };
        hwA[mt][1][3] = f16x2{ (_Float16)q3[2], (_Float16)q3[3] };
    }

    f32x16 acc0 = {}, acc1 = {}, acc2 = {};

    // ---------------- K loop: 65 k1-steps, 2 ksteps each ----------------
    const uint4* bp = Bf + lane;
    #pragma unroll 2
    for (int k1 = 0; k1 < 65; ++k1) {
        U4 bf0, bf1;
        bf0.u = bp[(2 * k1) * 64];
        bf1.u = bp[(2 * k1 + 1) * 64];
        u16 t0 = myT[k1 * STRIDE_T + l31];
        u16 t1 = myT[k1 * STRIDE_T + 32 + l31];
        u16 t2 = myT[k1 * STRIDE_T + 64 + l31];
        #pragma unroll
        for (int mt = 0; mt < 3; ++mt) {
            union { u16 u; _Float16 f; } cv;
            cv.u = (mt == 0) ? t0 : (mt == 1) ? t1 : t2;
            f16x2 hh = { cv.f, cv.f };
            HU A;
            #pragma unroll
            for (int rr = 0; rr < 4; ++rr) A.h2[rr] = hh * hwA[mt][0][rr];
            if (mt == 0)      acc0 = __builtin_amdgcn_mfma_f32_32x32x16_f16(A.h8, bf0.h, acc0, 0, 0, 0);
            else if (mt == 1) acc1 = __builtin_amdgcn_mfma_f32_32x32x16_f16(A.h8, bf0.h, acc1, 0, 0, 0);
            else              acc2 = __builtin_amdgcn_mfma_f32_32x32x16_f16(A.h8, bf0.h, acc2, 0, 0, 0);
            #pragma unroll
            for (int rr = 0; rr < 4; ++rr) A.h2[rr] = hh * hwA[mt][1][rr];
            if (mt == 0)      acc0 = __builtin_amdgcn_mfma_f32_32x32x16_f16(A.h8, bf1.h, acc0, 0, 0, 0);
            else if (mt == 1) acc1 = __builtin_amdgcn_mfma_f32_32x32x16_f16(A.h8, bf1.h, acc1, 0, 0, 0);
            else              acc2 = __builtin_amdgcn_mfma_f32_32x32x16_f16(A.h8, bf1.h, acc2, 0, 0, 0);
        }
    }

    // ---------------- store messages ----------------
    #pragma unroll
    for (int mt = 0; mt < 3; ++mt) {
        #pragma unroll
        for (int r = 0; r < 16; ++r) {
            int row = (r & 3) + 8 * (r >> 2) + 4 * h;
            int e = tileBase + mt * 32 + row;
            float v = (mt == 0) ? acc0[r] : (mt == 1) ? acc1[r] : acc2[r];
            if (e < E) out[(size_t)e * 32 + l31] = v;
        }
    }
}

extern "C" void kernel_launch(void* const* d_in, const int* in_sizes, int n_in,
                              void* d_out, int out_size, void* d_ws, size_t ws_size,
                              hipStream_t stream)
{
    // inputs: 0=h_v (unused), 1=h_w, 2=edge_features, 3=W1, 4=b1, 5=W2, 6=b2
    const float* h_w = (const float*)d_in[1];
    const float* ef  = (const float*)d_in[2];
    const float* W1  = (const float*)d_in[3];
    const float* b1  = (const float*)d_in[4];
    const float* W2  = (const float*)d_in[5];
    const float* b2  = (const float*)d_in[6];
    float* out = (float*)d_out;
    const int E = in_sizes[1] / 32;
    u16* ws = (u16*)d_ws;   // needs 135,168 B

    prep_kernel<<<33, 256, 0, stream>>>(W1, W2, b2, ws);

    const int blocks = (E + 4 * 96 - 1) / (4 * 96);
    edge_kernel<<<blocks, 256, 0, stream>>>(h_w, ef, b1, ws, out, E);
}

// Round 2
// 47.293 us; speedup vs baseline: 1.0401x; 1.0401x over previous
//
#include <hip/hip_runtime.h>

typedef unsigned short u16;
typedef _Float16 f16x2 __attribute__((ext_vector_type(2)));
typedef _Float16 f16x8 __attribute__((ext_vector_type(8)));
typedef float    f32x4  __attribute__((ext_vector_type(4)));
typedef float    f32x16 __attribute__((ext_vector_type(16)));

// Fragment k-map convention (same for A and B operands, so any within-lane
// permutation cancels in the MFMA contraction):
//   k_local(lane, j) = (lane>>5)*4 + (j&3) + 8*(j>>2),  j = 0..7
// D layout (measured m74/m101): col = lane&31, row = (r&3) + 8*(r>>2) + 4*(lane>>5)

union U4 { uint4 u; f16x8 h; u16 s[8]; };
union HU { f16x2 h2[4]; f16x8 h8; };

// ---------------------------------------------------------------------------
// Prep kernel: lay out W2flat (2080 x 32, f16) + W1 (16 x 64, f16) in MFMA
// B-fragment order into d_ws.
//   W2flat[kk][i] = kk < 2048 ? W2[kk>>5][i*32 + (kk&31)] : b2[i*32 + kk-2048]
// Bf slot (k2, lane): 8 f16 at ws + (k2*64 + lane)*8,  kk = k2*16 + k_local
// W1f slot (nt, lane): at ws + (8320 + nt*64 + lane)*8, col = nt*32 + (lane&31)
// ---------------------------------------------------------------------------
__global__ void prep_kernel(const float* __restrict__ W1,
                            const float* __restrict__ W2,
                            const float* __restrict__ b2,
                            u16* __restrict__ ws)
{
    int id = blockIdx.x * 256 + threadIdx.x;
    if (id < 8320) {                       // 130 ksteps * 64 lanes
        int k2 = id >> 6, l = id & 63;
        int h = l >> 5, col = l & 31;
        U4 o;
        #pragma unroll
        for (int g = 0; g < 2; ++g) {
            int base4 = k2 * 16 + g * 8 + h * 4;   // 4-aligned, no 32-straddle
            f32x4 v;
            if (base4 < 2048) {
                int k1 = base4 >> 5, j32 = base4 & 31;
                v = *(const f32x4*)&W2[k1 * 1024 + col * 32 + j32];
            } else {
                v = *(const f32x4*)&b2[col * 32 + (base4 - 2048)];
            }
            #pragma unroll
            for (int j = 0; j < 4; ++j)
                o.h[g * 4 + j] = (_Float16)v[j];
        }
        *(uint4*)(ws + id * 8) = o.u;
    } else if (id < 8448) {                // W1 fragments: 2 ntiles * 64 lanes
        int idx = id - 8320;
        int nt = idx >> 6, l = idx & 63;
        int h = l >> 5, col = nt * 32 + (l & 31);
        U4 o;
        #pragma unroll
        for (int g = 0; g < 2; ++g)
            #pragma unroll
            for (int j = 0; j < 4; ++j) {
                int k = g * 8 + h * 4 + j;
                o.h[g * 4 + j] = (_Float16)W1[k * 64 + col];
            }
        *(uint4*)(ws + id * 8) = o.u;
    }
}

// ---------------------------------------------------------------------------
// Main kernel: 4 waves/block, 64 edges/wave (2 M-tiles of 32).
//   - LDS 34.8 KB/block -> 4 blocks/CU -> ~16 waves/CU (vs 51.2 KB / 3 / 19%)
//   - B fragments: 4-deep rotating register prefetch pipeline (8-12 loads in
//     flight incl. unroll) to cover ~250-cycle L2 latency.
//   - hdnT rows: 1-deep LDS prefetch.
// Wave-private LDS slice (stride 66 u16: write banks (l31*33)%32 all-distinct,
// read 2-way-free). No __syncthreads anywhere.
// ---------------------------------------------------------------------------
#define STRIDE_T 66
#define SLICE_T  4352   // u16 per wave (need 64*66+64 = 4288)

__global__ __launch_bounds__(256, 4) void edge_kernel(
    const float* __restrict__ h_w,
    const float* __restrict__ ef,
    const float* __restrict__ b1,
    const u16*  __restrict__ ws,
    float* __restrict__ out,
    int E)
{
    __shared__ alignas(16) u16 ldsT[4 * SLICE_T];   // 34816 B
    const int tid  = threadIdx.x;
    const int lane = tid & 63;
    const int wv   = tid >> 6;
    const int l31  = lane & 31;
    const int h    = lane >> 5;
    const int tileBase = (blockIdx.x * 4 + wv) * 64;
    if (tileBase >= E) return;
    u16* myT = ldsT + wv * SLICE_T;

    const uint4* Bf  = (const uint4*)ws;
    const uint4* W1f = (const uint4*)(ws + 8320 * 8);
    const uint4* bp  = Bf + lane;

    // ---- B pipeline prologue: 8 loads in flight before layer-1 even runs ----
    U4 pipe[4][2];
    #pragma unroll
    for (int p = 0; p < 4; ++p) {
        pipe[p][0].u = bp[(2 * p) * 64];
        pipe[p][1].u = bp[(2 * p + 1) * 64];
    }

    // ---------------- layer 1: hdn = relu(ef @ W1 + b1) ----------------
    U4 w0, w1;
    w0.u = W1f[lane];
    w1.u = W1f[64 + lane];
    const float bb0 = b1[l31], bb1 = b1[32 + l31];
    #pragma unroll
    for (int mt = 0; mt < 2; ++mt) {
        int e = tileBase + mt * 32 + l31;
        bool ok = e < E;
        f32x4 g0 = {}, g1 = {};
        if (ok) {
            g0 = *(const f32x4*)&ef[e * 16 + h * 4];
            g1 = *(const f32x4*)&ef[e * 16 + 8 + h * 4];
        }
        U4 a;
        #pragma unroll
        for (int j = 0; j < 4; ++j) {
            a.h[j]     = (_Float16)g0[j];
            a.h[4 + j] = (_Float16)g1[j];
        }
        f32x16 c0 = {}, c1 = {};
        c0 = __builtin_amdgcn_mfma_f32_32x32x16_f16(a.h, w0.h, c0, 0, 0, 0);
        c1 = __builtin_amdgcn_mfma_f32_32x32x16_f16(a.h, w1.h, c1, 0, 0, 0);
        // relu + bias, pack edge-pairs, transposed write hdnT[k1][e_local]
        #pragma unroll
        for (int nt = 0; nt < 2; ++nt) {
            float bb = nt ? bb1 : bb0;
            int k1 = nt * 32 + l31;
            #pragma unroll
            for (int rp = 0; rp < 8; ++rp) {
                int r = 2 * rp;
                float v0 = fmaxf((nt ? c1[r]     : c0[r])     + bb, 0.f);
                float v1 = fmaxf((nt ? c1[r + 1] : c0[r + 1]) + bb, 0.f);
                f16x2 p = { (_Float16)v0, (_Float16)v1 };
                int e0 = mt * 32 + (r & 3) + 8 * (r >> 2) + 4 * h; // even
                *(unsigned int*)(myT + k1 * STRIDE_T + e0) =
                    __builtin_bit_cast(unsigned int, p);
            }
        }
    }
    // bias row k1 = 64: hdn = 1.0 (feeds the b2 rows of W2flat)
    if (lane < 32)
        *(unsigned int*)(myT + 64 * STRIDE_T + lane * 2) = 0x3C003C00u;

    // ---------------- load h_w fragments (f16, kept in regs) ----------------
    f16x2 hwA[2][2][4];
    #pragma unroll
    for (int mt = 0; mt < 2; ++mt) {
        int e = tileBase + mt * 32 + l31;
        bool ok = e < E;
        f32x4 q0 = {}, q1 = {}, q2 = {}, q3 = {};
        if (ok) {
            const float* hp = h_w + (size_t)e * 32 + h * 4;
            q0 = *(const f32x4*)(hp);
            q1 = *(const f32x4*)(hp + 8);
            q2 = *(const f32x4*)(hp + 16);
            q3 = *(const f32x4*)(hp + 24);
        }
        hwA[mt][0][0] = f16x2{ (_Float16)q0[0], (_Float16)q0[1] };
        hwA[mt][0][1] = f16x2{ (_Float16)q0[2], (_Float16)q0[3] };
        hwA[mt][0][2] = f16x2{ (_Float16)q1[0], (_Float16)q1[1] };
        hwA[mt][0][3] = f16x2{ (_Float16)q1[2], (_Float16)q1[3] };
        hwA[mt][1][0] = f16x2{ (_Float16)q2[0], (_Float16)q2[1] };
        hwA[mt][1][1] = f16x2{ (_Float16)q2[2], (_Float16)q2[3] };
        hwA[mt][1][2] = f16x2{ (_Float16)q3[0], (_Float16)q3[1] };
        hwA[mt][1][3] = f16x2{ (_Float16)q3[2], (_Float16)q3[3] };
    }

    f32x16 acc0 = {}, acc1 = {};

    // ---------------- K loop: 65 k1-steps, pipelined 4 deep ----------------
    u16 t0 = myT[l31];
    u16 t1 = myT[32 + l31];
    #pragma unroll 4
    for (int k1 = 0; k1 < 65; ++k1) {
        const int slot = k1 & 3;
        const u16 c0v = t0, c1v = t1;
        // prefetch next hdnT row (clamped; row 64 exists)
        {
            int kn = (k1 + 1 <= 64) ? k1 + 1 : 64;
            t0 = myT[kn * STRIDE_T + l31];
            t1 = myT[kn * STRIDE_T + 32 + l31];
        }
        #pragma unroll
        for (int mt = 0; mt < 2; ++mt) {
            union { u16 u; _Float16 f; } cv;
            cv.u = (mt == 0) ? c0v : c1v;
            f16x2 hh = { cv.f, cv.f };
            HU A;
            #pragma unroll
            for (int rr = 0; rr < 4; ++rr) A.h2[rr] = hh * hwA[mt][0][rr];
            if (mt == 0) acc0 = __builtin_amdgcn_mfma_f32_32x32x16_f16(A.h8, pipe[slot][0].h, acc0, 0, 0, 0);
            else         acc1 = __builtin_amdgcn_mfma_f32_32x32x16_f16(A.h8, pipe[slot][0].h, acc1, 0, 0, 0);
            #pragma unroll
            for (int rr = 0; rr < 4; ++rr) A.h2[rr] = hh * hwA[mt][1][rr];
            if (mt == 0) acc0 = __builtin_amdgcn_mfma_f32_32x32x16_f16(A.h8, pipe[slot][1].h, acc0, 0, 0, 0);
            else         acc1 = __builtin_amdgcn_mfma_f32_32x32x16_f16(A.h8, pipe[slot][1].h, acc1, 0, 0, 0);
        }
        // refill this slot with k1+4 (clamped; redundant tail loads harmless)
        {
            int kp = (k1 + 4 <= 64) ? k1 + 4 : 64;
            pipe[slot][0].u = bp[(2 * kp) * 64];
            pipe[slot][1].u = bp[(2 * kp + 1) * 64];
        }
    }

    // ---------------- store messages ----------------
    #pragma unroll
    for (int mt = 0; mt < 2; ++mt) {
        #pragma unroll
        for (int r = 0; r < 16; ++r) {
            int row = (r & 3) + 8 * (r >> 2) + 4 * h;
            int e = tileBase + mt * 32 + row;
            float v = (mt == 0) ? acc0[r] : acc1[r];
            if (e < E) out[(size_t)e * 32 + l31] = v;
        }
    }
}

extern "C" void kernel_launch(void* const* d_in, const int* in_sizes, int n_in,
                              void* d_out, int out_size, void* d_ws, size_t ws_size,
                              hipStream_t stream)
{
    // inputs: 0=h_v (unused), 1=h_w, 2=edge_features, 3=W1, 4=b1, 5=W2, 6=b2
    const float* h_w = (const float*)d_in[1];
    const float* ef  = (const float*)d_in[2];
    const float* W1  = (const float*)d_in[3];
    const float* b1  = (const float*)d_in[4];
    const float* W2  = (const float*)d_in[5];
    const float* b2  = (const float*)d_in[6];
    float* out = (float*)d_out;
    const int E = in_sizes[1] / 32;
    u16* ws = (u16*)d_ws;   // needs 135,168 B

    prep_kernel<<<33, 256, 0, stream>>>(W1, W2, b2, ws);

    const int blocks = (E + 4 * 64 - 1) / (4 * 64);
    edge_kernel<<<blocks, 256, 0, stream>>>(h_w, ef, b1, ws, out, E);
}